// Round 2
// baseline (239.879 us; speedup 1.0000x reference)
//
#include <hip/hip_runtime.h>
#include <stdint.h>

static constexpr int B = 32, S = 2048, F = 768;
static constexpr int CS = 128;            // chunk length along s
static constexpr int NCH = S / CS;        // 16 chunks
static constexpr int FT = F / 4;          // 192 threads (4 features/thread)

__device__ __forceinline__ uint32_t getw(const uint4& v, int w) {
    switch (w) { case 0: return v.x; case 1: return v.y; case 2: return v.z; default: return v.w; }
}

// ---------------- Pass A: masks -> 128-bit per-(b,chunk,feature) obs bitmasks
__global__ __launch_bounds__(FT) void passA(const int* __restrict__ masks, uint4* __restrict__ bm) {
    const int blk = blockIdx.x;                 // b*NCH + c
    const int b = blk / NCH, c = blk % NCH;
    const int j = threadIdx.x;                  // features 4j..4j+3
    const int4* mp = reinterpret_cast<const int4*>(masks + ((size_t)b * S + (size_t)c * CS) * F) + j;
    uint32_t r[4][4];
    #pragma unroll
    for (int w = 0; w < 4; ++w) {
        uint32_t a0 = 0, a1 = 0, a2 = 0, a3 = 0;
        #pragma unroll 8
        for (int k2 = 0; k2 < 32; ++k2) {
            int4 mv = mp[(size_t)(w * 32 + k2) * (F / 4)];
            uint32_t bit = 1u << k2;
            if (mv.x) a0 |= bit;
            if (mv.y) a1 |= bit;
            if (mv.z) a2 |= bit;
            if (mv.w) a3 |= bit;
        }
        r[w][0] = a0; r[w][1] = a1; r[w][2] = a2; r[w][3] = a3;
    }
    uint4* op = bm + (size_t)blk * F + 4 * j;
    #pragma unroll
    for (int q = 0; q < 4; ++q)
        op[q] = make_uint4(r[0][q], r[1][q], r[2][q], r[3][q]);
}

// ---------------- Pass B: cross-chunk carry scan (fwd: last obs ts before chunk; bwd: first obs ts after chunk)
__global__ void passB(const float* __restrict__ ts, const uint4* __restrict__ bm,
                      float* __restrict__ fwdc, float* __restrict__ bwdc) {
    int idx = blockIdx.x * blockDim.x + threadIdx.x;    // b*F + f
    if (idx >= B * F) return;
    int b = idx / F, f = idx - b * F;
    const float* tsb = ts + (size_t)b * S;
    float carry = tsb[0];                               // virtual obs at index 0
    for (int c = 0; c < NCH; ++c) {
        fwdc[((size_t)b * NCH + c) * F + f] = carry;
        uint4 v = bm[((size_t)b * NCH + c) * F + f];
        int base = c * CS;
        if (v.w)      carry = tsb[base + 96 + (31 - __clz((int)v.w))];
        else if (v.z) carry = tsb[base + 64 + (31 - __clz((int)v.z))];
        else if (v.y) carry = tsb[base + 32 + (31 - __clz((int)v.y))];
        else if (v.x) carry = tsb[base +      (31 - __clz((int)v.x))];
    }
    carry = tsb[S - 1];                                 // virtual obs at index s-1
    for (int c = NCH - 1; c >= 0; --c) {
        bwdc[((size_t)b * NCH + c) * F + f] = carry;
        uint4 v = bm[((size_t)b * NCH + c) * F + f];
        int base = c * CS;
        if (v.x)      carry = tsb[base +      (__ffs((int)v.x) - 1)];
        else if (v.y) carry = tsb[base + 32 + (__ffs((int)v.y) - 1)];
        else if (v.z) carry = tsb[base + 64 + (__ffs((int)v.z) - 1)];
        else if (v.w) carry = tsb[base + 96 + (__ffs((int)v.w) - 1)];
    }
}

// ---------------- Pass C: closed-form delta evaluation, writes fwd+bwd planes.
// NOTE: backward plane is stored in FLIPPED coordinates (reference never un-flips it):
//       out1[b, S-1-k, f] = ts[next_obs(k)] - ts[k]
__global__ __launch_bounds__(FT) void passC(const float* __restrict__ ts, const uint4* __restrict__ bm,
                                            const float* __restrict__ fwdc, const float* __restrict__ bwdc,
                                            float* __restrict__ out0, float* __restrict__ out1) {
    const int blk = blockIdx.x;
    const int b = blk / NCH, c = blk % NCH;
    const int j = threadIdx.x;
    __shared__ float tss[CS];
    for (int k = threadIdx.x; k < CS; k += FT) tss[k] = ts[(size_t)b * S + (size_t)c * CS + k];
    __syncthreads();

    const uint4* bp = bm + (size_t)blk * F + 4 * j;
    uint4 bv0 = bp[0], bv1 = bp[1], bv2 = bp[2], bv3 = bp[3];
    float4 pv = *reinterpret_cast<const float4*>(fwdc + (size_t)blk * F + 4 * j);
    float4 nv = *reinterpret_cast<const float4*>(bwdc + (size_t)blk * F + 4 * j);
    float p0 = pv.x, p1 = pv.y, p2 = pv.z, p3 = pv.w;
    float n0 = nv.x, n1 = nv.y, n2 = nv.z, n3 = nv.w;
    float4* o0 = reinterpret_cast<float4*>(out0 + ((size_t)b * S + (size_t)c * CS) * F) + j;
    float4* o1 = reinterpret_cast<float4*>(out1 + (size_t)b * S * F) + j;   // indexed by flipped row below

    // forward: delta_t = ts[t] - ts[last obs < t]
    #pragma unroll
    for (int w = 0; w < 4; ++w) {
        uint32_t b0 = getw(bv0, w), b1 = getw(bv1, w), b2 = getw(bv2, w), b3 = getw(bv3, w);
        #pragma unroll 8
        for (int k2 = 0; k2 < 32; ++k2) {
            int k = w * 32 + k2;
            float t = tss[k];
            o0[(size_t)k * (F / 4)] = make_float4(t - p0, t - p1, t - p2, t - p3);
            p0 = ((b0 >> k2) & 1u) ? t : p0;
            p1 = ((b1 >> k2) & 1u) ? t : p1;
            p2 = ((b2 >> k2) & 1u) ? t : p2;
            p3 = ((b3 >> k2) & 1u) ? t : p3;
        }
    }
    // backward: value at original k is ts[first obs > k] - ts[k]; stored at flipped row S-1-k
    #pragma unroll
    for (int w = 3; w >= 0; --w) {
        uint32_t b0 = getw(bv0, w), b1 = getw(bv1, w), b2 = getw(bv2, w), b3 = getw(bv3, w);
        #pragma unroll 8
        for (int k2 = 31; k2 >= 0; --k2) {
            int k = w * 32 + k2;
            float t = tss[k];
            int rr = (S - 1) - (c * CS + k);
            o1[(size_t)rr * (F / 4)] = make_float4(n0 - t, n1 - t, n2 - t, n3 - t);
            n0 = ((b0 >> k2) & 1u) ? t : n0;
            n1 = ((b1 >> k2) & 1u) ? t : n1;
            n2 = ((b2 >> k2) & 1u) ? t : n2;
            n3 = ((b3 >> k2) & 1u) ? t : n3;
        }
    }
}

// ---------------- Pass D: backward X = flip(encoded_data, axis=1), float4 copy
__global__ __launch_bounds__(FT) void passD(const float4* __restrict__ x, float4* __restrict__ o2) {
    const int r0 = blockIdx.x * 4;
    const int j = threadIdx.x;
    #pragma unroll
    for (int i = 0; i < 4; ++i) {
        int r = r0 + i;                     // global row b*S + t
        int b = r >> 11, t = r & (S - 1);   // S = 2048
        int sr = (b << 11) + (S - 1 - t);
        o2[(size_t)r * (F / 4) + j] = x[(size_t)sr * (F / 4) + j];
    }
}

// ---------------- Fallback (no workspace): serial per-(b,f) scans
__global__ void fallbackK(const float* __restrict__ ts, const int* __restrict__ masks,
                          float* __restrict__ out0, float* __restrict__ out1) {
    int idx = blockIdx.x * blockDim.x + threadIdx.x;
    if (idx >= B * F) return;
    int b = idx / F, f = idx - b * F;
    const float* tsb = ts + (size_t)b * S;
    const int* mb = masks + (size_t)b * S * F + f;
    float* o0 = out0 + (size_t)b * S * F + f;
    float* o1 = out1 + (size_t)b * S * F + f;
    float prev = tsb[0];
    for (int t = 0; t < S; ++t) {
        float tt = tsb[t];
        o0[(size_t)t * F] = tt - prev;
        if (mb[(size_t)t * F]) prev = tt;
    }
    float nxt = tsb[S - 1];
    for (int t = S - 1; t >= 0; --t) {
        float tt = tsb[t];
        o1[(size_t)(S - 1 - t) * F] = nxt - tt;   // flipped coordinates
        if (mb[(size_t)t * F]) nxt = tt;
    }
}

extern "C" void kernel_launch(void* const* d_in, const int* in_sizes, int n_in,
                              void* d_out, int out_size, void* d_ws, size_t ws_size,
                              hipStream_t stream) {
    const float* ts    = (const float*)d_in[0];
    const float* x     = (const float*)d_in[1];
    const int*   masks = (const int*)d_in[2];
    float* out = (float*)d_out;
    const size_t N = (size_t)B * S * F;

    const size_t bm_bytes    = (size_t)B * NCH * F * sizeof(uint4);
    const size_t carry_elems = (size_t)B * NCH * F;
    const size_t needed      = bm_bytes + 2 * carry_elems * sizeof(float);

    if (ws_size >= needed) {
        uint4* bm   = (uint4*)d_ws;
        float* fwdc = (float*)((char*)d_ws + bm_bytes);
        float* bwdc = fwdc + carry_elems;
        passA<<<B * NCH, FT, 0, stream>>>(masks, bm);
        passB<<<(B * F + 255) / 256, 256, 0, stream>>>(ts, bm, fwdc, bwdc);
        passC<<<B * NCH, FT, 0, stream>>>(ts, bm, fwdc, bwdc, out, out + N);
    } else {
        fallbackK<<<(B * F + 255) / 256, 256, 0, stream>>>(ts, masks, out, out + N);
    }
    passD<<<(B * S) / 4, FT, 0, stream>>>((const float4*)x, (float4*)(out + 2 * N));
}

// Round 3
// 238.166 us; speedup vs baseline: 1.0072x; 1.0072x over previous
//
#include <hip/hip_runtime.h>
#include <stdint.h>

static constexpr int B = 32, S = 2048, F = 768;
static constexpr int SC = 64;            // rows per block
static constexpr int NSC = S / SC;       // 32 sub-chunks
static constexpr int F4 = F / 4;         // 192 (row stride in float4/int4)
static constexpr int FT = F4;            // 192 threads, 4 features each

// One fused kernel: forward deltas + backward deltas (flipped) + flipped-X copy.
// Closed form: fwd[t] = ts[t] - ts[last obs < t (virtual 0)]
//              bwd stored at S-1-t:  ts[first obs > t (virtual S-1)] - ts[t]
__global__ __launch_bounds__(FT) void fusedK(const float* __restrict__ ts,
                                             const float4* __restrict__ x,
                                             const int4* __restrict__ masks,
                                             float* __restrict__ out) {
    const int blk = blockIdx.x;
    const int b  = blk >> 5;                 // / NSC
    const int sc = blk & (NSC - 1);
    const int g0 = sc * SC;
    const int j  = threadIdx.x;
    const float* tsb = ts + (size_t)b * S;
    const int4* mbase = masks + (size_t)b * S * F4 + j;

    __shared__ float tss[SC];
    if (threadIdx.x < SC) tss[threadIdx.x] = tsb[g0 + threadIdx.x];
    __syncthreads();

    // ---- forward carry: ts of last obs at row < g0 (virtual obs at row 0)
    float t0v = tsb[0];
    float p0 = t0v, p1 = t0v, p2 = t0v, p3 = t0v;
    if (g0 > 0) {
        unsigned um = 0xFu;
        int r = g0 - 1;
        while (um && r >= 0) {
            int rl = (r - 7 > 0) ? r - 7 : 0;
            int nn = r - rl + 1;
            int4 mv[8];
            #pragma unroll
            for (int q = 0; q < 8; ++q) if (q < nn) mv[q] = mbase[(size_t)(r - q) * F4];
            #pragma unroll
            for (int q = 0; q < 8; ++q) if (q < nn) {
                float t = tsb[r - q];                    // broadcast, cache-hit
                if ((um & 1u) && mv[q].x) { p0 = t; um &= ~1u; }
                if ((um & 2u) && mv[q].y) { p1 = t; um &= ~2u; }
                if ((um & 4u) && mv[q].z) { p2 = t; um &= ~4u; }
                if ((um & 8u) && mv[q].w) { p3 = t; um &= ~8u; }
            }
            r = rl - 1;
        }
    }

    // ---- backward carry: ts of first obs at row >= g0+SC (virtual obs at row S-1)
    float tev = tsb[S - 1];
    float n0 = tev, n1 = tev, n2 = tev, n3 = tev;
    if (g0 + SC < S) {
        unsigned um = 0xFu;
        int r = g0 + SC;
        while (um && r < S) {
            int rh = (r + 7 < S - 1) ? r + 7 : S - 1;
            int nn = rh - r + 1;
            int4 mv[8];
            #pragma unroll
            for (int q = 0; q < 8; ++q) if (q < nn) mv[q] = mbase[(size_t)(r + q) * F4];
            #pragma unroll
            for (int q = 0; q < 8; ++q) if (q < nn) {
                float t = tsb[r + q];
                if ((um & 1u) && mv[q].x) { n0 = t; um &= ~1u; }
                if ((um & 2u) && mv[q].y) { n1 = t; um &= ~2u; }
                if ((um & 4u) && mv[q].z) { n2 = t; um &= ~4u; }
                if ((um & 8u) && mv[q].w) { n3 = t; um &= ~8u; }
            }
            r = rh + 1;
        }
    }

    const size_t N4 = (size_t)B * S * F4;    // plane size in float4
    float4* o0 = reinterpret_cast<float4*>(out) + (size_t)(b * S + g0) * F4 + j;
    float4* o1b = reinterpret_cast<float4*>(out) + N4 + (size_t)b * S * F4 + j;       // indexed by flipped row
    float4* o2 = reinterpret_cast<float4*>(out) + 2 * N4 + (size_t)(b * S + g0) * F4 + j;
    const float4* xb = x + (size_t)b * S * F4 + j;

    // ---- main forward pass over own 64 rows: write fwd deltas, collect obs bits
    uint32_t a0 = 0, a1 = 0, a2 = 0, a3 = 0;    // rows g0..g0+31
    #pragma unroll
    for (int k = 0; k < 32; ++k) {
        int4 mv = mbase[(size_t)(g0 + k) * F4];
        float t = tss[k];
        o0[(size_t)k * F4] = make_float4(t - p0, t - p1, t - p2, t - p3);
        uint32_t bit = 1u << k;
        if (mv.x) { a0 |= bit; p0 = t; }
        if (mv.y) { a1 |= bit; p1 = t; }
        if (mv.z) { a2 |= bit; p2 = t; }
        if (mv.w) { a3 |= bit; p3 = t; }
    }
    uint32_t c0 = 0, c1 = 0, c2 = 0, c3 = 0;    // rows g0+32..g0+63
    #pragma unroll
    for (int k = 32; k < 64; ++k) {
        int4 mv = mbase[(size_t)(g0 + k) * F4];
        float t = tss[k];
        o0[(size_t)k * F4] = make_float4(t - p0, t - p1, t - p2, t - p3);
        uint32_t bit = 1u << (k - 32);
        if (mv.x) { c0 |= bit; p0 = t; }
        if (mv.y) { c1 |= bit; p1 = t; }
        if (mv.z) { c2 |= bit; p2 = t; }
        if (mv.w) { c3 |= bit; p3 = t; }
    }

    // ---- backward pass (descending) from bit-words; fuse flipped-X copy.
    // o1 value for original row k' = g0+k goes to flipped row S-1-k'.
    // o2 row k' <- x row S-1-k'.
    #pragma unroll
    for (int k = 63; k >= 32; --k) {
        float t = tss[k];
        size_t fr = (size_t)(S - 1 - g0 - k) * F4;   // flipped-row offset (ascending as k descends)
        float4 xv = xb[fr];
        o1b[fr] = make_float4(n0 - t, n1 - t, n2 - t, n3 - t);
        o2[(size_t)k * F4] = xv;
        uint32_t bit = 1u << (k - 32);
        if (c0 & bit) n0 = t;
        if (c1 & bit) n1 = t;
        if (c2 & bit) n2 = t;
        if (c3 & bit) n3 = t;
    }
    #pragma unroll
    for (int k = 31; k >= 0; --k) {
        float t = tss[k];
        size_t fr = (size_t)(S - 1 - g0 - k) * F4;
        float4 xv = xb[fr];
        o1b[fr] = make_float4(n0 - t, n1 - t, n2 - t, n3 - t);
        o2[(size_t)k * F4] = xv;
        uint32_t bit = 1u << k;
        if (a0 & bit) n0 = t;
        if (a1 & bit) n1 = t;
        if (a2 & bit) n2 = t;
        if (a3 & bit) n3 = t;
    }
}

extern "C" void kernel_launch(void* const* d_in, const int* in_sizes, int n_in,
                              void* d_out, int out_size, void* d_ws, size_t ws_size,
                              hipStream_t stream) {
    const float* ts    = (const float*)d_in[0];
    const float4* x    = (const float4*)d_in[1];
    const int4*  masks = (const int4*)d_in[2];
    float* out = (float*)d_out;
    fusedK<<<B * NSC, FT, 0, stream>>>(ts, x, masks, out);
}

// Round 4
// 237.983 us; speedup vs baseline: 1.0080x; 1.0008x over previous
//
#include <hip/hip_runtime.h>
#include <stdint.h>

static constexpr int B = 32, S = 2048, F = 768;
static constexpr int SC = 64;            // rows per delta block
static constexpr int NSC = S / SC;       // 32 sub-chunks per batch
static constexpr int F4 = F / 4;         // 192 (row stride in float4/int4)
static constexpr int FT = F4;            // 192 threads, 4 features each

// Grid = 2048 blocks: even blocks do delta work for pair=blk/2, odd blocks do
// the flip-copy for the same chunk. Cheap copy waves (low VGPR) co-reside with
// delta waves and keep HBM busy while delta waves sit in probe/carry latency.
__global__ __launch_bounds__(FT) void fusedK(const float* __restrict__ ts,
                                             const float4* __restrict__ x,
                                             const int4* __restrict__ masks,
                                             float* __restrict__ out) {
    const int blk = blockIdx.x;
    const int pair = blk >> 1;               // 0..1023 : (b, sc)
    const int b  = pair >> 5;                // / NSC
    const int sc = pair & (NSC - 1);
    const int g0 = sc * SC;
    const int j  = threadIdx.x;
    const size_t N4 = (size_t)B * S * F4;    // plane size in float4

    if (blk & 1) {
        // ---------------- flip-copy block: o2[b, g0+k, :] = x[b, S-1-(g0+k), :]
        const float4* xb = x + (size_t)b * S * F4 + j;
        float4* o2 = reinterpret_cast<float4*>(out) + 2 * N4 + (size_t)(b * S + g0) * F4 + j;
        #pragma unroll 8
        for (int k = 0; k < SC; ++k) {
            o2[(size_t)k * F4] = xb[(size_t)(S - 1 - g0 - k) * F4];
        }
        return;
    }

    // ---------------- delta block ----------------
    const float* tsb = ts + (size_t)b * S;
    const int4* mbase = masks + (size_t)b * S * F4 + j;

    __shared__ float tss[SC];
    if (j < SC) tss[j] = tsb[g0 + j];
    __syncthreads();

    // ---- Phase 1: bulk-collect own 64 mask rows into bit-words (groups of 8
    //      independent loads -> no load->store chains later).
    uint32_t a0 = 0, a1 = 0, a2 = 0, a3 = 0;   // rows g0..g0+31
    uint32_t c0 = 0, c1 = 0, c2 = 0, c3 = 0;   // rows g0+32..g0+63
    #pragma unroll
    for (int g = 0; g < 8; ++g) {
        int4 mv[8];
        #pragma unroll
        for (int q = 0; q < 8; ++q) mv[q] = mbase[(size_t)(g0 + g * 8 + q) * F4];
        #pragma unroll
        for (int q = 0; q < 8; ++q) {
            const int k = g * 8 + q;
            const uint32_t bit = 1u << (k & 31);
            if (k < 32) {
                if (mv[q].x) a0 |= bit;
                if (mv[q].y) a1 |= bit;
                if (mv[q].z) a2 |= bit;
                if (mv[q].w) a3 |= bit;
            } else {
                if (mv[q].x) c0 |= bit;
                if (mv[q].y) c1 |= bit;
                if (mv[q].z) c2 |= bit;
                if (mv[q].w) c3 |= bit;
            }
        }
    }

    // ---- Phase 2: forward carry probe (last obs ts at row < g0; virtual at 0)
    float t0v = tsb[0];
    float p0 = t0v, p1 = t0v, p2 = t0v, p3 = t0v;
    if (g0 > 0) {
        unsigned um = 0xFu;
        int r = g0 - 1;
        while (um && r >= 0) {
            int rl = (r - 7 > 0) ? r - 7 : 0;
            int nn = r - rl + 1;
            int4 mv[8];
            #pragma unroll
            for (int q = 0; q < 8; ++q) if (q < nn) mv[q] = mbase[(size_t)(r - q) * F4];
            #pragma unroll
            for (int q = 0; q < 8; ++q) if (q < nn) {
                float t = tsb[r - q];
                if ((um & 1u) && mv[q].x) { p0 = t; um &= ~1u; }
                if ((um & 2u) && mv[q].y) { p1 = t; um &= ~2u; }
                if ((um & 4u) && mv[q].z) { p2 = t; um &= ~4u; }
                if ((um & 8u) && mv[q].w) { p3 = t; um &= ~8u; }
            }
            r = rl - 1;
        }
    }

    // ---- Phase 3: backward carry probe (first obs ts at row >= g0+SC; virtual at S-1)
    float tev = tsb[S - 1];
    float n0 = tev, n1 = tev, n2 = tev, n3 = tev;
    if (g0 + SC < S) {
        unsigned um = 0xFu;
        int r = g0 + SC;
        while (um && r < S) {
            int rh = (r + 7 < S - 1) ? r + 7 : S - 1;
            int nn = rh - r + 1;
            int4 mv[8];
            #pragma unroll
            for (int q = 0; q < 8; ++q) if (q < nn) mv[q] = mbase[(size_t)(r + q) * F4];
            #pragma unroll
            for (int q = 0; q < 8; ++q) if (q < nn) {
                float t = tsb[r + q];
                if ((um & 1u) && mv[q].x) { n0 = t; um &= ~1u; }
                if ((um & 2u) && mv[q].y) { n1 = t; um &= ~2u; }
                if ((um & 4u) && mv[q].z) { n2 = t; um &= ~4u; }
                if ((um & 8u) && mv[q].w) { n3 = t; um &= ~8u; }
            }
            r = rh + 1;
        }
    }

    // ---- Phase 4: forward-delta stores (pure store loop, bit-driven carries)
    float4* o0 = reinterpret_cast<float4*>(out) + (size_t)(b * S + g0) * F4 + j;
    #pragma unroll
    for (int k = 0; k < 32; ++k) {
        float t = tss[k];
        o0[(size_t)k * F4] = make_float4(t - p0, t - p1, t - p2, t - p3);
        const uint32_t bit = 1u << k;
        if (a0 & bit) p0 = t;
        if (a1 & bit) p1 = t;
        if (a2 & bit) p2 = t;
        if (a3 & bit) p3 = t;
    }
    #pragma unroll
    for (int k = 32; k < 64; ++k) {
        float t = tss[k];
        o0[(size_t)k * F4] = make_float4(t - p0, t - p1, t - p2, t - p3);
        const uint32_t bit = 1u << (k - 32);
        if (c0 & bit) p0 = t;
        if (c1 & bit) p1 = t;
        if (c2 & bit) p2 = t;
        if (c3 & bit) p3 = t;
    }

    // ---- Phase 5: backward-delta stores, in FLIPPED coordinates:
    //      out1[b, S-1-(g0+k), :] = ts[first obs > g0+k] - ts[g0+k]
    float4* o1b = reinterpret_cast<float4*>(out) + N4 + (size_t)b * S * F4 + j;
    #pragma unroll
    for (int k = 63; k >= 32; --k) {
        float t = tss[k];
        size_t fr = (size_t)(S - 1 - g0 - k) * F4;
        o1b[fr] = make_float4(n0 - t, n1 - t, n2 - t, n3 - t);
        const uint32_t bit = 1u << (k - 32);
        if (c0 & bit) n0 = t;
        if (c1 & bit) n1 = t;
        if (c2 & bit) n2 = t;
        if (c3 & bit) n3 = t;
    }
    #pragma unroll
    for (int k = 31; k >= 0; --k) {
        float t = tss[k];
        size_t fr = (size_t)(S - 1 - g0 - k) * F4;
        o1b[fr] = make_float4(n0 - t, n1 - t, n2 - t, n3 - t);
        const uint32_t bit = 1u << k;
        if (a0 & bit) n0 = t;
        if (a1 & bit) n1 = t;
        if (a2 & bit) n2 = t;
        if (a3 & bit) n3 = t;
    }
}

extern "C" void kernel_launch(void* const* d_in, const int* in_sizes, int n_in,
                              void* d_out, int out_size, void* d_ws, size_t ws_size,
                              hipStream_t stream) {
    const float* ts    = (const float*)d_in[0];
    const float4* x    = (const float4*)d_in[1];
    const int4*  masks = (const int4*)d_in[2];
    float* out = (float*)d_out;
    fusedK<<<2 * B * NSC, FT, 0, stream>>>(ts, x, masks, out);
}

// Round 6
// 194.056 us; speedup vs baseline: 1.2361x; 1.2264x over previous
//
#include <hip/hip_runtime.h>
#include <stdint.h>

static constexpr int B = 32, S = 2048, F = 768;
static constexpr int SC = 64;            // rows per delta block
static constexpr int NSC = S / SC;       // 32 sub-chunks per batch
static constexpr int F4 = F / 4;         // 192 (row stride in float4/int4)
static constexpr int FT = F4;            // 192 threads, 4 features each

typedef float v4f __attribute__((ext_vector_type(4)));   // native vector for nt builtins

__device__ __forceinline__ v4f mk4(float a, float b, float c, float d) {
    v4f v; v.x = a; v.y = b; v.z = c; v.w = d; return v;
}

// ---------------- Delta kernel: fwd deltas + bwd deltas (flipped coords) ----
__global__ __launch_bounds__(FT) void deltaK(const float* __restrict__ ts,
                                             const int4* __restrict__ masks,
                                             float* __restrict__ out) {
    const int pair = blockIdx.x;             // 0..1023 : (b, sc)
    const int b  = pair >> 5;                // / NSC
    const int sc = pair & (NSC - 1);
    const int g0 = sc * SC;
    const int j  = threadIdx.x;
    const size_t N4 = (size_t)B * S * F4;    // plane size in float4

    const float* tsb = ts + (size_t)b * S;
    const int4* mbase = masks + (size_t)b * S * F4 + j;

    __shared__ float tss[SC];
    if (j < SC) tss[j] = tsb[g0 + j];
    __syncthreads();

    // ---- Phase 1: bulk-collect own 64 mask rows into bit-words
    uint32_t a0 = 0, a1 = 0, a2 = 0, a3 = 0;   // rows g0..g0+31
    uint32_t c0 = 0, c1 = 0, c2 = 0, c3 = 0;   // rows g0+32..g0+63
    #pragma unroll
    for (int g = 0; g < 8; ++g) {
        int4 mv[8];
        #pragma unroll
        for (int q = 0; q < 8; ++q) mv[q] = mbase[(size_t)(g0 + g * 8 + q) * F4];
        #pragma unroll
        for (int q = 0; q < 8; ++q) {
            const int k = g * 8 + q;
            const uint32_t bit = 1u << (k & 31);
            if (k < 32) {
                if (mv[q].x) a0 |= bit;
                if (mv[q].y) a1 |= bit;
                if (mv[q].z) a2 |= bit;
                if (mv[q].w) a3 |= bit;
            } else {
                if (mv[q].x) c0 |= bit;
                if (mv[q].y) c1 |= bit;
                if (mv[q].z) c2 |= bit;
                if (mv[q].w) c3 |= bit;
            }
        }
    }

    // ---- Phase 2: forward carry probe (last obs ts at row < g0; virtual at 0)
    float t0v = tsb[0];
    float p0 = t0v, p1 = t0v, p2 = t0v, p3 = t0v;
    if (g0 > 0) {
        unsigned um = 0xFu;
        int r = g0 - 1;
        while (um && r >= 0) {
            int rl = (r - 7 > 0) ? r - 7 : 0;
            int nn = r - rl + 1;
            int4 mv[8];
            #pragma unroll
            for (int q = 0; q < 8; ++q) if (q < nn) mv[q] = mbase[(size_t)(r - q) * F4];
            #pragma unroll
            for (int q = 0; q < 8; ++q) if (q < nn) {
                float t = tsb[r - q];
                if ((um & 1u) && mv[q].x) { p0 = t; um &= ~1u; }
                if ((um & 2u) && mv[q].y) { p1 = t; um &= ~2u; }
                if ((um & 4u) && mv[q].z) { p2 = t; um &= ~4u; }
                if ((um & 8u) && mv[q].w) { p3 = t; um &= ~8u; }
            }
            r = rl - 1;
        }
    }

    // ---- Phase 3: backward carry probe (first obs ts at row >= g0+SC; virtual at S-1)
    float tev = tsb[S - 1];
    float n0 = tev, n1 = tev, n2 = tev, n3 = tev;
    if (g0 + SC < S) {
        unsigned um = 0xFu;
        int r = g0 + SC;
        while (um && r < S) {
            int rh = (r + 7 < S - 1) ? r + 7 : S - 1;
            int nn = rh - r + 1;
            int4 mv[8];
            #pragma unroll
            for (int q = 0; q < 8; ++q) if (q < nn) mv[q] = mbase[(size_t)(r + q) * F4];
            #pragma unroll
            for (int q = 0; q < 8; ++q) if (q < nn) {
                float t = tsb[r + q];
                if ((um & 1u) && mv[q].x) { n0 = t; um &= ~1u; }
                if ((um & 2u) && mv[q].y) { n1 = t; um &= ~2u; }
                if ((um & 4u) && mv[q].z) { n2 = t; um &= ~4u; }
                if ((um & 8u) && mv[q].w) { n3 = t; um &= ~8u; }
            }
            r = rh + 1;
        }
    }

    // ---- Phase 4: forward-delta stores (nontemporal, bit-driven carries)
    v4f* o0 = reinterpret_cast<v4f*>(out) + (size_t)(b * S + g0) * F4 + j;
    #pragma unroll
    for (int k = 0; k < 32; ++k) {
        float t = tss[k];
        __builtin_nontemporal_store(mk4(t - p0, t - p1, t - p2, t - p3), &o0[(size_t)k * F4]);
        const uint32_t bit = 1u << k;
        if (a0 & bit) p0 = t;
        if (a1 & bit) p1 = t;
        if (a2 & bit) p2 = t;
        if (a3 & bit) p3 = t;
    }
    #pragma unroll
    for (int k = 32; k < 64; ++k) {
        float t = tss[k];
        __builtin_nontemporal_store(mk4(t - p0, t - p1, t - p2, t - p3), &o0[(size_t)k * F4]);
        const uint32_t bit = 1u << (k - 32);
        if (c0 & bit) p0 = t;
        if (c1 & bit) p1 = t;
        if (c2 & bit) p2 = t;
        if (c3 & bit) p3 = t;
    }

    // ---- Phase 5: backward-delta stores, FLIPPED coords:
    //      out1[b, S-1-(g0+k), :] = ts[first obs > g0+k] - ts[g0+k]
    v4f* o1b = reinterpret_cast<v4f*>(out) + N4 + (size_t)b * S * F4 + j;
    #pragma unroll
    for (int k = 63; k >= 32; --k) {
        float t = tss[k];
        size_t fr = (size_t)(S - 1 - g0 - k) * F4;
        __builtin_nontemporal_store(mk4(n0 - t, n1 - t, n2 - t, n3 - t), &o1b[fr]);
        const uint32_t bit = 1u << (k - 32);
        if (c0 & bit) n0 = t;
        if (c1 & bit) n1 = t;
        if (c2 & bit) n2 = t;
        if (c3 & bit) n3 = t;
    }
    #pragma unroll
    for (int k = 31; k >= 0; --k) {
        float t = tss[k];
        size_t fr = (size_t)(S - 1 - g0 - k) * F4;
        __builtin_nontemporal_store(mk4(n0 - t, n1 - t, n2 - t, n3 - t), &o1b[fr]);
        const uint32_t bit = 1u << k;
        if (a0 & bit) n0 = t;
        if (a1 & bit) n1 = t;
        if (a2 & bit) n2 = t;
        if (a3 & bit) n3 = t;
    }
}

// ---------------- Flat flip-copy kernel (fill-shaped): o2[i] = x[flip(i)] ----
static constexpr int CPY_BLOCKS = 2048;
__global__ __launch_bounds__(256) void copyK(const v4f* __restrict__ x,
                                             v4f* __restrict__ o2) {
    const size_t N4 = (size_t)B * S * F4;
    const size_t stride = (size_t)CPY_BLOCKS * 256;
    for (size_t i = (size_t)blockIdx.x * 256 + threadIdx.x; i < N4; i += stride) {
        // i -> (b, t, f4); src row flipped: S-1-t
        size_t row = i / F4;                 // b*S + t
        size_t f   = i - row * F4;
        size_t t   = row & (S - 1);          // S power of 2
        size_t src = (row - t + (S - 1 - t)) * F4 + f;
        __builtin_nontemporal_store(__builtin_nontemporal_load(&x[src]), &o2[i]);
    }
}

extern "C" void kernel_launch(void* const* d_in, const int* in_sizes, int n_in,
                              void* d_out, int out_size, void* d_ws, size_t ws_size,
                              hipStream_t stream) {
    const float* ts    = (const float*)d_in[0];
    const v4f* x       = (const v4f*)d_in[1];
    const int4*  masks = (const int4*)d_in[2];
    float* out = (float*)d_out;
    const size_t N4 = (size_t)B * S * F4;
    deltaK<<<B * NSC, FT, 0, stream>>>(ts, masks, out);
    copyK<<<CPY_BLOCKS, 256, 0, stream>>>(x, reinterpret_cast<v4f*>(out) + 2 * N4);
}